// Round 9
// baseline (221.444 us; speedup 1.0000x reference)
//
#include <hip/hip_runtime.h>
#include <hip/hip_bf16.h>
#include <math.h>

#define EDIM 256
#define HDIM 256
#define BDIM 64
#define TDIM 2048
#define NC   64
#define TC   32
#define CPB  4      // chunks per persistent block

typedef __attribute__((ext_vector_type(8)))  short  short8;
typedef __attribute__((ext_vector_type(4)))  float  floatx4;
typedef __attribute__((ext_vector_type(4)))  unsigned int uintx4;

__device__ __forceinline__ unsigned short f2bf(float f) {
    unsigned int u = __float_as_uint(f);
    u += 0x7FFFu + ((u >> 16) & 1u);      // RNE
    return (unsigned short)(u >> 16);
}
__device__ __forceinline__ unsigned int pk2(float a, float b) {
    return (unsigned int)f2bf(a) | ((unsigned int)f2bf(b) << 16);
}
__device__ __forceinline__ float sigm(float x) {
    return __builtin_amdgcn_rcpf(1.f + __expf(-x));
}
__device__ __forceinline__ float tanh_fast(float x) {
    return fmaf(-2.f, __builtin_amdgcn_rcpf(1.f + __expf(2.f * x)), 1.f);
}

// Fused pack: blocks [0,256) -> Wp fragment-pack; blocks [256,4256) -> emb bf16.
// Wp layout: [hg][nt][ks][lane][8] bf16; value = Wq[(ks*32+q*8+j)*768 + c],
// c = z: hg*64+(nt&3)*16+col, f: 256 + same.  (unchanged, proven r2-r8)
__global__ __launch_bounds__(256) void qrnn_pack(
    const float* __restrict__ Wq, const float* __restrict__ emb,
    unsigned short* __restrict__ Wp, unsigned short* __restrict__ ebf)
{
    const int bx = blockIdx.x;
    if (bx < 256) {
        const int nt = (bx >> 3) & 7;
        const int hg = bx >> 6;
        const int ks = bx & 7;
        const int t = threadIdx.x;
        const int lane = t >> 2, pj = t & 3;
        const int col = lane & 15, q = lane >> 4;
        const int h = hg * 64 + (nt & 3) * 16 + col;
        const int c = (nt < 4) ? h : (HDIM + h);
        const int k = ks * 32 + q * 8 + pj * 2;
        unsigned int v = pk2(Wq[k * (3 * HDIM) + c], Wq[(k + 1) * (3 * HDIM) + c]);
        *(unsigned int*)(Wp + (size_t)bx * 512 + lane * 8 + pj * 2) = v;
    } else {
        size_t i = ((size_t)(bx - 256) * 256 + threadIdx.x) * 8;
        floatx4 a = *(const floatx4*)(emb + i);
        floatx4 b = *(const floatx4*)(emb + i + 4);
        uintx4 o = {pk2(a.x, a.y), pk2(a.z, a.w), pk2(b.x, b.y), pk2(b.z, b.w)};
        *(uintx4*)(ebf + i) = o;
    }
}

// Main: wave tile m=128 (4 batches x 32 t) x n=32 (z+f pair for 16 h).
// Block = 4 n-split waves -> m128 x n128; grid 1024 (2/CU, 2 passes).
// acc = 64 regs (no spill at 2 waves/SIMD); per-wave LDS B-reads per K-step = 2
// vs 16 MFMAs (LDS:MFMA ~1.24 -> MfmaUtil ceiling ~80%).
// B staged once via global_load_lds; A gathered from bf16 emb, ring-3/distance-2.
template<bool EMBBF>
__global__ __launch_bounds__(256, 2) void qrnn_mfma(
    const int* __restrict__ X, const float* __restrict__ emb,
    const unsigned short* __restrict__ ebf, const unsigned short* __restrict__ Wp,
    const float* __restrict__ bq, float* __restrict__ wsA, float* __restrict__ wsB)
{
    __shared__ __align__(16) short Bsh[32768];   // 64 KB: [nt][ks][lane][8]

    const int tid = threadIdx.x;
    const int bid = blockIdx.x;                  // 0..1023
    const int hg  = (bid >> 3) & 3;              // hg-siblings share an XCD slot
    const int g   = ((bid >> 5) << 3) | (bid & 7);   // 0..255
    const int cgi = g & 15, bg = g >> 4;         // 16 chunk-groups x 16 batch-groups

    const int lane = tid & 63, nw = tid >> 6;    // nw = wave's n-pair (z: nw, f: nw+4)
    const int col = lane & 15, q = lane >> 4;

    // Stage B slice (64 KB, all ks) once.
    const unsigned short* wpb = Wp + (size_t)hg * 32768;
#pragma unroll
    for (int i = 0; i < 16; ++i) {
        const int ch = nw * 16 + i;          // wave-uniform
        __builtin_amdgcn_global_load_lds(
            (const __attribute__((address_space(1))) unsigned int*)(wpb + ch * 512 + lane * 8),
            (__attribute__((address_space(3))) unsigned int*)(Bsh + ch * 512),
            16, 0, 0);
    }

    const int b0 = bg * 4;
    // rotating xid sets: current chunk + next chunk (8 m-tiles each)
    int xc[8], xn[8];
    auto loadX = [&](int cc, int* arr) {
#pragma unroll
        for (int mt = 0; mt < 8; ++mt)
            arr[mt] = X[(b0 + (mt >> 1)) * TDIM + cc * TC + (mt & 1) * 16 + col];
    };
    loadX(cgi * CPB + 0, xc);
    loadX(cgi * CPB + 1, xn);

    const int hbase = hg * 64;
    const float bzv = bq[hbase + nw * 16 + col];
    const float bfv = bq[HDIM + hbase + nw * 16 + col];

    short8 abuf[3][8];
    auto fetchA = [&](const int* xa, int ks, int slot) {
#pragma unroll
        for (int mt = 0; mt < 8; ++mt) {
            const unsigned int vo = (unsigned int)xa[mt] * EDIM + q * 8 + ks * 32;
            if constexpr (EMBBF) {
                abuf[slot][mt] = *(const short8*)(ebf + vo);
            } else {
                const float* ap = emb + vo;
                floatx4 f0 = *(const floatx4*)ap;
                floatx4 f1 = *(const floatx4*)(ap + 4);
                uintx4 p = {pk2(f0.x, f0.y), pk2(f0.z, f0.w),
                            pk2(f1.x, f1.y), pk2(f1.z, f1.w)};
                abuf[slot][mt] = *(short8*)&p;
            }
        }
    };

    floatx4 acc[8][2];
#pragma unroll
    for (int mt = 0; mt < 8; ++mt) {
        acc[mt][0] = (floatx4){0.f, 0.f, 0.f, 0.f};
        acc[mt][1] = (floatx4){0.f, 0.f, 0.f, 0.f};
    }

    fetchA(xc, 0, 0);
    fetchA(xc, 1, 1);
    __syncthreads();   // waits LDS staging too

#pragma unroll
    for (int c = 0; c < CPB; ++c) {
#pragma unroll
        for (int ks = 0; ks < 8; ++ks) {
            const int s = c * 8 + ks;
            if (s + 2 < CPB * 8) {
                const int t = s + 2;
                fetchA(((t >> 3) == c) ? xc : xn, t & 7, t % 3);
            }
            short8 bf0 = *(const short8*)(Bsh + (nw * 8 + ks) * 512 + lane * 8);
            short8 bf1 = *(const short8*)(Bsh + ((nw + 4) * 8 + ks) * 512 + lane * 8);
            const int sl = s % 3;
#pragma unroll
            for (int mt = 0; mt < 8; ++mt) {
                acc[mt][0] = __builtin_amdgcn_mfma_f32_16x16x32_bf16(abuf[sl][mt], bf0, acc[mt][0], 0, 0, 0);
                acc[mt][1] = __builtin_amdgcn_mfma_f32_16x16x32_bf16(abuf[sl][mt], bf1, acc[mt][1], 0, 0, 0);
            }
        }

        // Epilogue chunk cc: mt = bt*2 + th; t = th*16 + q*4 + j; h = hbase+nw*16+col.
        const int cc = cgi * CPB + c;
#pragma unroll
        for (int bt = 0; bt < 4; ++bt) {
            float Aseg[2], Bseg[2];
#pragma unroll
            for (int th = 0; th < 2; ++th) {
                float Ac = 1.f, Bc = 0.f;
#pragma unroll
                for (int j = 0; j < 4; ++j) {
                    float z = tanh_fast(acc[bt * 2 + th][0][j] + bzv);
                    float f = sigm(acc[bt * 2 + th][1][j] + bfv);
                    Ac = f * Ac;
                    Bc = fmaf(f, Bc - z, z);       // f*Bc + (1-f)*z
                }
                Aseg[th] = Ac; Bseg[th] = Bc;
            }
#pragma unroll
            for (int st = 0; st < 2; ++st) {
                const int msk = 16 << st;
                const bool self_earlier = ((q >> st) & 1) == 0;
#pragma unroll
                for (int th = 0; th < 2; ++th) {
                    float Ap = __shfl_xor(Aseg[th], msk, 64);
                    float Bp = __shfl_xor(Bseg[th], msk, 64);
                    Bseg[th] = self_earlier ? fmaf(Ap, Bseg[th], Bp)
                                            : fmaf(Aseg[th], Bp, Bseg[th]);
                    Aseg[th] = Aseg[th] * Ap;
                }
            }
            // combine halves (th=0 is t 0..15, earlier)
            const float Afin = Aseg[1] * Aseg[0];
            const float Bfin = fmaf(Aseg[1], Bseg[0], Bseg[1]);
            if (q == bt) {
                const size_t r = ((size_t)cc * BDIM + b0 + bt) * HDIM + hbase + nw * 16 + col;
                wsA[r] = Afin;
                wsB[r] = Bfin;
            }
        }

#pragma unroll
        for (int mt = 0; mt < 8; ++mt) {
            acc[mt][0] = (floatx4){0.f, 0.f, 0.f, 0.f};
            acc[mt][1] = (floatx4){0.f, 0.f, 0.f, 0.f};
        }
        // rotate xid sets
        if (c < CPB - 1) {
#pragma unroll
            for (int mt = 0; mt < 8; ++mt) xc[mt] = xn[mt];
            if (c < CPB - 2) loadX(cgi * CPB + c + 2, xn);
        }
    }
}

// Combine chunk (A,B) pairs + o-gate at t=T-1 + output dot. (unchanged)
__global__ __launch_bounds__(256) void qrnn_combine(
    const float* __restrict__ wsA, const float* __restrict__ wsB,
    const float* __restrict__ c0, const int* __restrict__ X,
    const float* __restrict__ emb, const float* __restrict__ Wq,
    const float* __restrict__ bq, const float* __restrict__ Wout,
    const float* __restrict__ bout, float* __restrict__ out)
{
    const int b = blockIdx.x;
    const int h = threadIdx.x;

    float c = c0[b * HDIM + h];
    for (int c8 = 0; c8 < NC; c8 += 8) {
        float a[8], bb[8];
#pragma unroll
        for (int i = 0; i < 8; ++i) {
            size_t base = ((size_t)(c8 + i) * BDIM + b) * HDIM + h;
            a[i]  = wsA[base];
            bb[i] = wsB[base];
        }
#pragma unroll
        for (int i = 0; i < 8; ++i) c = fmaf(a[i], c, bb[i]);
    }

    __shared__ float xs[EDIM];
    int idx = X[b * TDIM + (TDIM - 1)];
    xs[h] = emb[(size_t)idx * EDIM + h];
    __syncthreads();

    float acc = 0.f;
#pragma unroll 16
    for (int e = 0; e < EDIM; ++e)
        acc = fmaf(xs[e], Wq[e * (3 * HDIM) + 2 * HDIM + h], acc);

    float o  = 1.f / (1.f + expf(-(acc + bq[2 * HDIM + h])));
    float hn = o * c;

    __shared__ float red[HDIM];
    red[h] = hn * Wout[h];
    __syncthreads();
    for (int s = HDIM / 2; s > 0; s >>= 1) {
        if (h < s) red[h] += red[h + s];
        __syncthreads();
    }
    if (h == 0) out[b] = red[0] + bout[0];
}

extern "C" void kernel_launch(void* const* d_in, const int* in_sizes, int n_in,
                              void* d_out, int out_size, void* d_ws, size_t ws_size,
                              hipStream_t stream) {
    const int*   X    = (const int*)d_in[0];
    const float* emb  = (const float*)d_in[1];
    const float* Wq   = (const float*)d_in[2];
    const float* bq   = (const float*)d_in[3];
    const float* c0   = (const float*)d_in[4];
    const float* Wout = (const float*)d_in[5];
    const float* bout = (const float*)d_in[6];
    float* out = (float*)d_out;

    float* wsA = (float*)d_ws;                        // [NC][B][H]
    float* wsB = wsA + (size_t)NC * BDIM * HDIM;      // [NC][B][H]
    unsigned short* Wp  = (unsigned short*)(wsB + (size_t)NC * BDIM * HDIM);  // 256 KB
    unsigned short* ebf = Wp + (size_t)256 * 512;     // 16.4 MB

    const size_t need_full = (size_t)2 * NC * BDIM * HDIM * 4
                           + (size_t)256 * 512 * 2
                           + (size_t)32000 * EDIM * 2;
    const bool full = ws_size >= need_full;

    const int emb_blocks = (32000 * EDIM / 8) / 256;   // 4000
    qrnn_pack<<<256 + (full ? emb_blocks : 0), 256, 0, stream>>>(Wq, emb, Wp, ebf);

    if (full) qrnn_mfma<true ><<<1024, 256, 0, stream>>>(X, emb, ebf, Wp, bq, wsA, wsB);
    else      qrnn_mfma<false><<<1024, 256, 0, stream>>>(X, emb, ebf, Wp, bq, wsA, wsB);

    qrnn_combine<<<BDIM, 256, 0, stream>>>(wsA, wsB, c0, X, emb, Wq, bq, Wout, bout, out);
}